// Round 21
// baseline (29.018 us; speedup 1.0000x reference)
//
#include <hip/hip_runtime.h>
#include <hip/hip_bf16.h>

typedef __attribute__((ext_vector_type(4))) float f32x4;
typedef __attribute__((ext_vector_type(8))) short s16x8;
typedef __attribute__((ext_vector_type(4))) short s16x4;
typedef unsigned int u32;

#define DHEAD 128
#define KVB 16             // kv rows per tile (fine-grained)
#define BLKQ 32            // q-rows per block = 2 q-slots x 16
#define NGRP 4             // in-block kv groups
#define KTB 4096           // bytes per 16-row K fragment tile
#define VTB 4096           // bytes per 16-row V fragment tile
#define LDSZ 66048         // 4 grps x 2 bufs x (4K K + 4K V) + 512B lred; 2 blocks/CU

__device__ __forceinline__ short f2bf(float x) {
    __hip_bfloat16 h = __float2bfloat16(x);
    return *reinterpret_cast<short*>(&h);
}

// K: unchanged 32-row fragment layout (a 32-row tile = two 16-row tiles
// back-to-back: 16-row tile tau at byte tau*4096; chunk kk at kk*1024;
// lane(g,qi) holds K[tau*16+qi][kk*32+g*8+e]).
// V: NEW 16-row tiles of s16x4 units: unit u = dg*64+lane (8 B each):
// V[tau*16 + g*4 + j][dg*16 + qi], j=0..3. Tile = 4 KB.
__global__ __launch_bounds__(256)
void prep_frag(const float* __restrict__ K, const float* __restrict__ V,
               const int* __restrict__ VL,
               short* __restrict__ Kz, short* __restrict__ Vz,
               int m, int NT32, int NT16, int nkf, int nvf) {
    const int i = blockIdx.x * 256 + threadIdx.x;
    if (i < nkf) {
        const int lane = i & 63;
        const int kk   = (i >> 6) & 3;
        const int s    = (i >> 8) & 1;
        const int rest = i >> 9;
        const int t = rest % NT32, b = rest / NT32;
        if (t * 32 >= VL[b]) return;
        const int qi = lane & 15, g = lane >> 4;
        const float* src = K + (size_t)(b * m + t * 32 + 16 * s + qi) * DHEAD + kk * 32 + g * 8;
        f32x4 a = *reinterpret_cast<const f32x4*>(src);
        f32x4 c = *reinterpret_cast<const f32x4*>(src + 4);
        s16x8 o;
        #pragma unroll
        for (int j = 0; j < 4; ++j) { o[j] = f2bf(a[j]); o[4 + j] = f2bf(c[j]); }
        *reinterpret_cast<s16x8*>(Kz + (size_t)i * 8) = o;
    } else {
        const int j = i - nkf;
        if (j < nvf) {
            const int lane = j & 63;
            const int dg   = (j >> 6) & 7;
            const int rest = j >> 9;
            const int tau = rest % NT16, b = rest / NT16;
            if (tau * KVB >= VL[b]) return;
            const int qi = lane & 15, g = lane >> 4;
            const float* vb = V + (size_t)(b * m + tau * KVB + g * 4) * DHEAD + dg * 16 + qi;
            s16x4 o;
            #pragma unroll
            for (int r = 0; r < 4; ++r) o[r] = f2bf(vb[(size_t)r * DHEAD]);
            *reinterpret_cast<s16x4*>(Vz + (size_t)j * 4) = o;
        }
    }
}

// Flash attention, fixed-origin softmax. 8 waves = 2 q-slots x 4 kv-groups,
// KVB=16, 64KB LDS -> TWO independent blocks per CU (4 waves/SIMD where a
// sibling block fills the SIMD during this block's barrier/L2-tail stalls —
// R16's 1-block/CU had no sibling, and its 16-wave barrier put the slowest
// group's L2 tail latency on every iteration's critical path). Grid 512 over
// 256 CUs: hardware greedy dispatch halves the vl-tail imbalance. PV uses the
// proven 16x16x32 MFMA with the pa upper half zeroed (absent kv 16..31).
// In-LDS merge of the 4 groups; no global partials, no combine kernel.
__global__ __launch_bounds__(512, 2)
void attn_fwd(const float* __restrict__ Q, const short* __restrict__ Kz,
              const short* __restrict__ Vz, const int* __restrict__ VL,
              float* __restrict__ O, int B, int n, int NT16) {
    extern __shared__ char lds[];

    const int tid   = threadIdx.x;
    const int lane  = tid & 63;
    const int wid   = tid >> 6;     // 0..7
    const int qslot = wid & 1;      // 16-row q sub-tile
    const int grp   = wid >> 1;     // kv group 0..3
    const int gl    = lane >> 4;    // 0..3
    const int qi    = lane & 15;

    // XCD-pinned decode: 2 batches/XCD -> bf16 KV stream L2-resident.
    const int nq = n / BLKQ;        // 32
    int b, qt;
    if ((B & 7) == 0) {
        const int xcd = blockIdx.x & 7;
        const int sub = blockIdx.x >> 3;
        const int bpx = B >> 3;
        b  = xcd * bpx + (sub % bpx);
        qt = sub / bpx;
    } else {
        b = blockIdx.x / nq; qt = blockIdx.x % nq;
    }

    const int vl = VL[b];
    const int nt = (vl + KVB - 1) >> 4;         // 16-row tiles, 1..64
    const int IT = (nt + NGRP - 1) / NGRP;      // uniform per-group iterations
    const int rowbase = b * n + qt * BLKQ + qslot * 16;

    // ---- Q fragments from f32, pre-scaled by 1/sqrt(d)*log2(e) ----
    const float qsc = 0.08838834764831845f * 1.4426950408889634f;
    s16x8 qf[4];
    {
        const float* qp = Q + (size_t)(rowbase + qi) * DHEAD + gl * 8;
        #pragma unroll
        for (int kk = 0; kk < 4; ++kk) {
            f32x4 a  = *reinterpret_cast<const f32x4*>(qp + kk * 32);
            f32x4 cc = *reinterpret_cast<const f32x4*>(qp + kk * 32 + 4);
            s16x8 s;
            #pragma unroll
            for (int j = 0; j < 4; ++j) { s[j] = f2bf(a[j] * qsc); s[4 + j] = f2bf(cc[j] * qsc); }
            qf[kk] = s;
        }
    }

    const char* KzB = (const char*)Kz + (size_t)b * NT16 * KTB;
    const char* VzB = (const char*)Vz + (size_t)b * NT16 * VTB;

    // group tile slab: grp*16KB + buf*8KB; K at +0, V at +4096.
    // DMA: qslot wave 0 stages the K 4KB, wave 1 the V 4KB (4 x 1KB each).
    auto DMA = [&](int buf, int tau) {
        const char* src = (qslot ? VzB : KzB) + (size_t)tau * 4096;
        char* dst = &lds[grp * 16384 + buf * 8192 + qslot * 4096];
        #pragma unroll
        for (int j = 0; j < 4; ++j) {
            __builtin_amdgcn_global_load_lds(
                (const __attribute__((address_space(1))) u32*)(src + j * 1024 + lane * 16),
                (__attribute__((address_space(3))) u32*)(dst + j * 1024), 16, 0, 0);
        }
    };

    f32x4 Oacc[8];
    #pragma unroll
    for (int dg = 0; dg < 8; ++dg) Oacc[dg] = 0.f;
    float llocal = 0.f;
    const int lb = lane * 16;

    // ---- prologue ----
    if (grp < nt) DMA(0, grp);
    __syncthreads();

    int cur = 0;
    #pragma unroll 1
    for (int i = 0; i < IT; ++i) {
        const int tau = grp + i * NGRP;
        const int tn  = tau + NGRP;
        if (tn < nt) DMA(cur ^ 1, tn);   // T3: issue next, drained at end-of-iter sync

        if (tau < nt) {
            const char* ksb = &lds[grp * 16384 + cur * 8192];
            const char* vsb = ksb + 4096;

            // ---- S^T = K16 * Q^T : 4 MFMA, Sacc rows kv = gl*4+r ----
            f32x4 Sacc = 0.f;
            __builtin_amdgcn_s_setprio(1);
            #pragma unroll
            for (int kk = 0; kk < 4; ++kk) {
                s16x8 kf = *reinterpret_cast<const s16x8*>(ksb + kk * 1024 + lb);
                Sacc = __builtin_amdgcn_mfma_f32_16x16x32_bf16(kf, qf[kk], Sacc, 0, 0, 0);
            }
            __builtin_amdgcn_s_setprio(0);

            // ---- valid_length mask (tail tile only) ----
            const int kvrem = vl - tau * KVB;
            if (kvrem < KVB) {
                #pragma unroll
                for (int r = 0; r < 4; ++r)
                    if (gl * 4 + r >= kvrem) Sacc[r] = -1e30f;
            }

            // ---- fixed-origin softmax numerator; upper pa half = 0 ----
            s16x8 pa;
            #pragma unroll
            for (int r = 0; r < 4; ++r) {
                const float e = __builtin_amdgcn_exp2f(fminf(Sacc[r], 60.f));
                llocal += e;
                pa[r]     = f2bf(e);
                pa[4 + r] = 0;
            }

            // ---- O += P * V : 16x16x32 MFMA, kv 16..31 zeroed via pa ----
            __builtin_amdgcn_s_setprio(1);
            #pragma unroll
            for (int dg = 0; dg < 8; ++dg) {
                s16x4 v4 = *reinterpret_cast<const s16x4*>(vsb + dg * 512 + lane * 8);
                s16x8 vf;
                vf[0] = v4[0]; vf[1] = v4[1]; vf[2] = v4[2]; vf[3] = v4[3];
                vf[4] = 0; vf[5] = 0; vf[6] = 0; vf[7] = 0;
                Oacc[dg] = __builtin_amdgcn_mfma_f32_16x16x32_bf16(pa, vf, Oacc[dg], 0, 0, 0);
            }
            __builtin_amdgcn_s_setprio(0);
        }

        __syncthreads();   // uniform across 8 waves; frees buf, drains DMA
        cur ^= 1;
    }

    // ---- merge the 4 kv-groups in LDS (fixed origin: plain sums) ----
    llocal += __shfl_xor(llocal, 16);
    llocal += __shfl_xor(llocal, 32);

    float* P    = (float*)lds;                 // slot s8=grp*2+qslot: 8KB each = 64KB
    float* lred = (float*)&lds[65536];         // [s8*16+qi], 512 B
    const int s8 = grp * 2 + qslot;
    {
        float* w = P + ((size_t)s8 * 8) * 256;
        #pragma unroll
        for (int dg = 0; dg < 8; ++dg)
            *reinterpret_cast<f32x4*>(w + dg * 256 + lane * 4) = Oacc[dg];
        if (gl == 0) lred[s8 * 16 + qi] = llocal;
    }
    __syncthreads();

    // each wave merges + writes dg in {2*grp, 2*grp+1} for its qslot rows
    {
        float ltot = 0.f;
        #pragma unroll
        for (int g2 = 0; g2 < 4; ++g2) ltot += lred[(g2 * 2 + qslot) * 16 + qi];
        const float linv = 1.0f / ltot;
        const float l0 = __shfl(linv, gl * 4 + 0);
        const float l1 = __shfl(linv, gl * 4 + 1);
        const float l2 = __shfl(linv, gl * 4 + 2);
        const float l3 = __shfl(linv, gl * 4 + 3);

        float* Ob = O + (size_t)rowbase * DHEAD;
        #pragma unroll
        for (int k = 0; k < 2; ++k) {
            const int dg = grp * 2 + k;
            f32x4 acc = 0.f;
            #pragma unroll
            for (int g2 = 0; g2 < 4; ++g2) {
                const float* rp = P + ((size_t)(g2 * 2 + qslot) * 8 + dg) * 256 + lane * 4;
                f32x4 v = *reinterpret_cast<const f32x4*>(rp);
                acc[0] += v[0]; acc[1] += v[1]; acc[2] += v[2]; acc[3] += v[3];
            }
            Ob[(gl * 4 + 0) * DHEAD + dg * 16 + qi] = acc[0] * l0;
            Ob[(gl * 4 + 1) * DHEAD + dg * 16 + qi] = acc[1] * l1;
            Ob[(gl * 4 + 2) * DHEAD + dg * 16 + qi] = acc[2] * l2;
            Ob[(gl * 4 + 3) * DHEAD + dg * 16 + qi] = acc[3] * l3;
        }
    }
}

extern "C" void kernel_launch(void* const* d_in, const int* in_sizes, int n_in,
                              void* d_out, int out_size, void* d_ws, size_t ws_size,
                              hipStream_t stream) {
    const float* Q  = (const float*)d_in[0];
    const float* K  = (const float*)d_in[1];
    const float* V  = (const float*)d_in[2];
    const int*   VL = (const int*)d_in[3];
    float* O = (float*)d_out;

    const int B = in_sizes[3];
    const int n = in_sizes[0] / (B * DHEAD);
    const int m = in_sizes[1] / (B * DHEAD);
    const int NT32 = m / 32;                    // 32
    const int NT16 = m / KVB;                   // 64

    short* Kz = (short*)d_ws;                                   // 4 MB
    short* Vz = Kz + (size_t)B * NT16 * (KTB / 2);              // 4 MB

    const int nkf = B * NT32 * 512;             // 16B K units
    const int nvf = B * NT16 * 512;             // 8B V units
    prep_frag<<<(nkf + nvf + 255) / 256, 256, 0, stream>>>(K, V, VL, Kz, Vz,
                                                           m, NT32, NT16, nkf, nvf);

    hipFuncSetAttribute((const void*)attn_fwd,
                        hipFuncAttributeMaxDynamicSharedMemorySize, LDSZ);
    const int grid = B * (n / BLKQ);            // 512 -> 2 blocks/CU
    attn_fwd<<<grid, 512, LDSZ, stream>>>(Q, Kz, Vz, VL, O, B, n, NT16);
}

// Round 22
// 26.520 us; speedup vs baseline: 1.0942x; 1.0942x over previous
//
#include <hip/hip_runtime.h>
#include <hip/hip_bf16.h>

typedef __attribute__((ext_vector_type(4))) float f32x4;
typedef __attribute__((ext_vector_type(8))) short s16x8;
typedef unsigned int u32;

#define DHEAD 128
#define KVB 32             // kv rows per tile
#define BLKQ 64            // q-rows per block = 4 q-slots x 16
#define NGRP 4             // in-block kv groups (4 waves each)
#define TILB 8192          // bytes per fragment-ordered 32x128 bf16 tile
#define LDSZ 131072        // 4 groups x 2 bufs x (8KB K + 8KB V)

__device__ __forceinline__ short f2bf(float x) {
    __hip_bfloat16 h = __float2bfloat16(x);
    return *reinterpret_cast<short*>(&h);
}

// Rewrite K,V (f32 row-major) -> bf16 MFMA-FRAGMENT order, 32-row tiles:
//  K tile t: unit u=(s*4+kk)*64+lane, lane=(g,qi): K[t*32+16s+qi][kk*32+g*8+e]
//  V tile t: unit u=dg*64+lane: e<4: V[t*32+g*4+e][dg*16+qi]; e>=4: +16 rows
__global__ __launch_bounds__(256)
void prep_frag(const float* __restrict__ K, const float* __restrict__ V,
               const int* __restrict__ VL,
               short* __restrict__ Kz, short* __restrict__ Vz, int m, int NT, int nkf) {
    const int i = blockIdx.x * 256 + threadIdx.x;
    if (i < nkf) {
        const int lane = i & 63;
        const int kk   = (i >> 6) & 3;
        const int s    = (i >> 8) & 1;
        const int rest = i >> 9;
        const int t = rest % NT, b = rest / NT;
        if (t * KVB >= VL[b]) return;
        const int qi = lane & 15, g = lane >> 4;
        const float* src = K + (size_t)(b * m + t * KVB + 16 * s + qi) * DHEAD + kk * 32 + g * 8;
        f32x4 a = *reinterpret_cast<const f32x4*>(src);
        f32x4 c = *reinterpret_cast<const f32x4*>(src + 4);
        s16x8 o;
        #pragma unroll
        for (int j = 0; j < 4; ++j) { o[j] = f2bf(a[j]); o[4 + j] = f2bf(c[j]); }
        *reinterpret_cast<s16x8*>(Kz + (size_t)i * 8) = o;
    } else {
        const int j = i - nkf;
        if (j < nkf) {
            const int lane = j & 63;
            const int dg   = (j >> 6) & 7;
            const int rest = j >> 9;
            const int t = rest % NT, b = rest / NT;
            if (t * KVB >= VL[b]) return;
            const int qi = lane & 15, g = lane >> 4;
            const float* vb = V + (size_t)(b * m + t * KVB + g * 4) * DHEAD + dg * 16 + qi;
            s16x8 o;
            #pragma unroll
            for (int r = 0; r < 4; ++r) {
                o[r]     = f2bf(vb[(size_t)r * DHEAD]);
                o[4 + r] = f2bf(vb[(size_t)(16 + r) * DHEAD]);
            }
            *reinterpret_cast<s16x8*>(Vz + (size_t)j * 8) = o;
        }
    }
}

// Flash attention, fixed-origin softmax, IN-BLOCK kv-split (R16, measured best
// 26.6us): 16 waves = 4 q-slots x 4 kv-groups; group g owns tiles t = g (mod 4)
// with a group-private double-buffered LDS pipeline. Each SIMD hosts 4 waves
// from 4 DIFFERENT groups -> independent work hides stalls. Uniform iteration
// count keeps s_barrier legal. Final merge is an in-LDS sum (fixed origin =>
// associative), no workspace partials, no combine kernel.
__global__ __launch_bounds__(1024, 4)
void attn_fwd(const float* __restrict__ Q, const short* __restrict__ Kz,
              const short* __restrict__ Vz, const int* __restrict__ VL,
              float* __restrict__ O, int B, int n, int NT) {
    extern __shared__ char lds[];   // LDSZ bytes

    const int tid   = threadIdx.x;
    const int lane  = tid & 63;
    const int wid   = tid >> 6;     // 0..15
    const int qslot = wid & 3;      // q sub-tile (16 rows)
    const int grp   = wid >> 2;     // kv group 0..3
    const int gl    = lane >> 4;    // 0..3
    const int qi    = lane & 15;

    // XCD-pinned decode: 2 batches/XCD -> bf16 KV stream L2-resident.
    const int nq = n / BLKQ;        // 16
    int b, qt;
    if ((B & 7) == 0) {
        const int xcd = blockIdx.x & 7;
        const int sub = blockIdx.x >> 3;
        const int bpx = B >> 3;
        b  = xcd * bpx + (sub % bpx);
        qt = sub / bpx;
    } else {
        b = blockIdx.x / nq; qt = blockIdx.x % nq;
    }

    const int vl = VL[b];
    const int nt = (vl + KVB - 1) / KVB;        // tiles (1..32)
    const int IT = (nt + NGRP - 1) / NGRP;      // uniform per-group iterations
    const int rowbase = b * n + qt * BLKQ + qslot * 16;

    // ---- Q fragments from f32, pre-scaled by 1/sqrt(d)*log2(e) ----
    const float qsc = 0.08838834764831845f * 1.4426950408889634f;
    s16x8 qf[4];
    {
        const float* qp = Q + (size_t)(rowbase + qi) * DHEAD + gl * 8;
        #pragma unroll
        for (int kk = 0; kk < 4; ++kk) {
            f32x4 a  = *reinterpret_cast<const f32x4*>(qp + kk * 32);
            f32x4 cc = *reinterpret_cast<const f32x4*>(qp + kk * 32 + 4);
            s16x8 s;
            #pragma unroll
            for (int j = 0; j < 4; ++j) { s[j] = f2bf(a[j] * qsc); s[4 + j] = f2bf(cc[j] * qsc); }
            qf[kk] = s;
        }
    }

    const char* KzB = (const char*)Kz + (size_t)b * NT * TILB;
    const char* VzB = (const char*)Vz + (size_t)b * NT * TILB;

    // group-private DMA: this wave stages 2KB of K + 2KB of V of its group's tile
    auto DMA = [&](int buf, int t) {
        const char* ks = KzB + (size_t)t * TILB;
        const char* vs = VzB + (size_t)t * TILB;
        char* dst = &lds[grp * 32768 + buf * 16384];
        const int off = qslot * 2048;
        #pragma unroll
        for (int j = 0; j < 2; ++j) {
            __builtin_amdgcn_global_load_lds(
                (const __attribute__((address_space(1))) u32*)(ks + off + j * 1024 + lane * 16),
                (__attribute__((address_space(3))) u32*)(dst + off + j * 1024), 16, 0, 0);
            __builtin_amdgcn_global_load_lds(
                (const __attribute__((address_space(1))) u32*)(vs + off + j * 1024 + lane * 16),
                (__attribute__((address_space(3))) u32*)(dst + 8192 + off + j * 1024), 16, 0, 0);
        }
    };

    f32x4 Oacc[8];
    #pragma unroll
    for (int dg = 0; dg < 8; ++dg) Oacc[dg] = 0.f;
    float llocal = 0.f;
    const int lb = lane * 16;

    // ---- prologue: each group stages its first tile ----
    if (grp < nt) DMA(0, grp);
    __syncthreads();

    int cur = 0;
    #pragma unroll 1
    for (int i = 0; i < IT; ++i) {
        const int t  = grp + i * NGRP;
        const int tn = t + NGRP;
        if (tn < nt) DMA(cur ^ 1, tn);   // T3: issue next, drained at end-of-iter sync

        if (t < nt) {
            const char* ksb = &lds[grp * 32768 + cur * 16384];
            const char* vsb = ksb + 8192;

            // ---- S^T = K * Q^T ----
            f32x4 Sacc[2];
            Sacc[0] = 0.f; Sacc[1] = 0.f;
            __builtin_amdgcn_s_setprio(1);
            #pragma unroll
            for (int s = 0; s < 2; ++s)
                #pragma unroll
                for (int kk = 0; kk < 4; ++kk) {
                    s16x8 kf = *reinterpret_cast<const s16x8*>(ksb + (s * 4 + kk) * 1024 + lb);
                    Sacc[s] = __builtin_amdgcn_mfma_f32_16x16x32_bf16(kf, qf[kk], Sacc[s], 0, 0, 0);
                }
            __builtin_amdgcn_s_setprio(0);

            // ---- valid_length mask (tail tile only) ----
            const int kvrem = vl - t * KVB;
            if (kvrem < KVB) {
                #pragma unroll
                for (int s = 0; s < 2; ++s)
                    #pragma unroll
                    for (int r = 0; r < 4; ++r)
                        if (s * 16 + gl * 4 + r >= kvrem) Sacc[s][r] = -1e30f;
            }

            // ---- fixed-origin softmax numerator ----
            s16x8 pa;
            #pragma unroll
            for (int s = 0; s < 2; ++s)
                #pragma unroll
                for (int r = 0; r < 4; ++r) {
                    const float e = __builtin_amdgcn_exp2f(fminf(Sacc[s][r], 60.f));
                    llocal += e;
                    pa[s * 4 + r] = f2bf(e);
                }

            // ---- O += P * V ----
            __builtin_amdgcn_s_setprio(1);
            #pragma unroll
            for (int dg = 0; dg < 8; ++dg) {
                s16x8 vf = *reinterpret_cast<const s16x8*>(vsb + dg * 1024 + lb);
                Oacc[dg] = __builtin_amdgcn_mfma_f32_16x16x32_bf16(pa, vf, Oacc[dg], 0, 0, 0);
            }
            __builtin_amdgcn_s_setprio(0);
        }

        __syncthreads();   // uniform across all 16 waves; frees buf, drains DMA
        cur ^= 1;
    }

    // ---- merge the 4 kv-groups in LDS (fixed origin: plain sums) ----
    llocal += __shfl_xor(llocal, 16);
    llocal += __shfl_xor(llocal, 32);

    float* red  = (float*)lds;                    // 3 x 32 KB O partials
    float* lred = (float*)&lds[98304];            // 3 x 64 l partials
    if (grp > 0) {
        float* w = red + (size_t)(grp - 1) * 8192 + qslot * 2048;
        #pragma unroll
        for (int dg = 0; dg < 8; ++dg)
            #pragma unroll
            for (int j = 0; j < 4; ++j)
                w[(gl * 4 + j) * 128 + dg * 16 + qi] = Oacc[dg][j];
        if (gl == 0) lred[(grp - 1) * 64 + qslot * 16 + qi] = llocal;
    }
    __syncthreads();

    if (grp == 0) {
        float ltot = llocal;
        #pragma unroll
        for (int g2 = 0; g2 < 3; ++g2) ltot += lred[g2 * 64 + qslot * 16 + qi];
        const float linv = 1.0f / ltot;
        const float l0 = __shfl(linv, gl * 4 + 0);
        const float l1 = __shfl(linv, gl * 4 + 1);
        const float l2 = __shfl(linv, gl * 4 + 2);
        const float l3 = __shfl(linv, gl * 4 + 3);
        float* Ob = O + (size_t)rowbase * DHEAD;
        #pragma unroll
        for (int dg = 0; dg < 8; ++dg) {
            float v0 = Oacc[dg][0], v1 = Oacc[dg][1], v2 = Oacc[dg][2], v3 = Oacc[dg][3];
            #pragma unroll
            for (int g2 = 0; g2 < 3; ++g2) {
                const float* rr = red + (size_t)g2 * 8192 + qslot * 2048;
                v0 += rr[(gl * 4 + 0) * 128 + dg * 16 + qi];
                v1 += rr[(gl * 4 + 1) * 128 + dg * 16 + qi];
                v2 += rr[(gl * 4 + 2) * 128 + dg * 16 + qi];
                v3 += rr[(gl * 4 + 3) * 128 + dg * 16 + qi];
            }
            Ob[(gl * 4 + 0) * DHEAD + dg * 16 + qi] = v0 * l0;
            Ob[(gl * 4 + 1) * DHEAD + dg * 16 + qi] = v1 * l1;
            Ob[(gl * 4 + 2) * DHEAD + dg * 16 + qi] = v2 * l2;
            Ob[(gl * 4 + 3) * DHEAD + dg * 16 + qi] = v3 * l3;
        }
    }
}

extern "C" void kernel_launch(void* const* d_in, const int* in_sizes, int n_in,
                              void* d_out, int out_size, void* d_ws, size_t ws_size,
                              hipStream_t stream) {
    const float* Q  = (const float*)d_in[0];
    const float* K  = (const float*)d_in[1];
    const float* V  = (const float*)d_in[2];
    const int*   VL = (const int*)d_in[3];
    float* O = (float*)d_out;

    const int B = in_sizes[3];
    const int n = in_sizes[0] / (B * DHEAD);
    const int m = in_sizes[1] / (B * DHEAD);
    const int NT = m / KVB;                     // 32

    short* Kz = (short*)d_ws;
    short* Vz = Kz + (size_t)B * NT * (TILB / 2);

    const int nkf = B * NT * 512;               // s16x8 units per tensor
    prep_frag<<<(2 * nkf + 255) / 256, 256, 0, stream>>>(K, V, VL, Kz, Vz, m, NT, nkf);

    hipFuncSetAttribute((const void*)attn_fwd,
                        hipFuncAttributeMaxDynamicSharedMemorySize, LDSZ);
    const int grid = B * (n / BLKQ);
    attn_fwd<<<grid, 1024, LDSZ, stream>>>(Q, Kz, Vz, VL, O, B, n, NT);
}